// Round 8
// baseline (349.019 us; speedup 1.0000x reference)
//
#include <hip/hip_runtime.h>
#include <hip/hip_bf16.h>

#define NN 10000      // nodes
#define NE 320000     // edges
#define HD 128        // h_dim
#define ED 16         // e_dim
#define HID 256       // hid_dim
#define KP 480        // A row: [x 128 | cnt*x 128 | sum_xj 128 | sum_soh 64 | sum_ea 16 | cnt 1 | pad 15]
#define AST 488       // LDS A-row stride (ushorts), 976B = 16B-aligned

typedef unsigned short ushort_t;
typedef __attribute__((ext_vector_type(8))) short short8;
typedef __attribute__((ext_vector_type(4))) float f32x4;

__device__ __forceinline__ float leaky(float v){ return v > 0.f ? v : 0.01f*v; }
__device__ __forceinline__ ushort_t f2bs(float v){
  __hip_bfloat16 b = __float2bfloat16(v);
  return *(ushort_t*)&b;
}
__device__ __forceinline__ unsigned pack2u(float a, float b){
  return (unsigned)f2bs(a) | ((unsigned)f2bs(b) << 16);
}
__device__ __forceinline__ float bl(unsigned u){ return __uint_as_float(u << 16); }
__device__ __forceinline__ float bh(unsigned u){ return __uint_as_float(u & 0xffff0000u); }
__device__ __forceinline__ float2 cvt2(unsigned u){ return make_float2(bl(u), bh(u)); }

// ---- merged setup: seed x->bf16 | edge count | wc_top transpose | WcT K-pad zeros ----
__global__ __launch_bounds__(256) void k_misc(const float* __restrict__ x, ushort_t* __restrict__ xb,
                                              const int* __restrict__ ii, int* __restrict__ cnt,
                                              const float* __restrict__ Wx, ushort_t* __restrict__ WcT){
  int t = blockIdx.x*256 + threadIdx.x;
  if (t < NN*HD){
    xb[t] = f2bs(x[t]);
  } else if (t < NN*HD + NE){
    atomicAdd(&cnt[ii[t - NN*HD]], 1);
  } else if (t < NN*HD + NE + 4*HD*HD){
    int u = t - NN*HD - NE;
    int l = u >> 14, r = (u >> 7) & 127, c = u & 127;
    WcT[((long)l*HD + c)*KP + r] = f2bs(Wx[(long)l*(HD+HID)*HD + r*HD + c]);
  } else {
    int u = t - NN*HD - NE - 4*HD*HD;     // 512 rows x 15 pad cols
    if (u < 4*HD*15){
      int row = u / 15, k = 465 + u % 15;
      WcT[(long)row*KP + k] = 0;
    }
  }
}

__global__ __launch_bounds__(256) void k_scan(const int* __restrict__ cnt, int* __restrict__ row_ptr){
  const int PER = 40;
  __shared__ int sh[256];
  int t = threadIdx.x;
  int base = t*PER;
  int s = 0;
  for (int k = 0; k < PER; ++k){ int idx = base+k; if (idx < NN) s += cnt[idx]; }
  sh[t] = s; __syncthreads();
  for (int off = 1; off < 256; off <<= 1){
    int v = (t >= off) ? sh[t-off] : 0;
    __syncthreads();
    sh[t] += v;
    __syncthreads();
  }
  int pre = sh[t] - s;
  for (int k = 0; k < PER; ++k){
    int idx = base+k;
    if (idx < NN){ row_ptr[idx] = pre; pre += cnt[idx]; }
  }
  if (t == 255) row_ptr[NN] = sh[255];
}

// ---- merged: CSR fill (blocks 0..1249) | wc_bot GEMM (blocks 1250..1293) ----
__global__ __launch_bounds__(256) void k_fillwc(const int* __restrict__ ii, const int* __restrict__ jj,
                                                const int* __restrict__ row_ptr, int* __restrict__ c2,
                                                int* __restrict__ sj, int* __restrict__ se,
                                                const float* __restrict__ Wm, const float* __restrict__ bm,
                                                const float* __restrict__ Wx, ushort_t* __restrict__ WcT){
  if (blockIdx.x < 1250){
    int e = blockIdx.x*256 + threadIdx.x;   // 1250*256 == NE exactly
    int a = ii[e];
    int p = atomicAdd(&c2[a], 1);
    int idx = row_ptr[a] + p;
    sj[idx] = jj[e];
    se[idx] = e;
    return;
  }
  __shared__ float a_s[16*36];
  __shared__ float w_s[16*128];
  int bi = blockIdx.x - 1250;
  int t  = threadIdx.x;
  int rb = (bi % 11) * 32;
  int l  = bi / 11;
  int lr = t >> 4, lk = t & 15;
  int wcc = t & 127, wk = t >> 7;
  int cg = t & 31, rg = t >> 5;
  const float* Wxb = Wx + (long)l*(HD+HID)*HD + HD*HD;
  float acc[4][4];
  #pragma unroll
  for (int i = 0; i < 4; ++i)
    #pragma unroll
    for (int j = 0; j < 4; ++j) acc[i][j] = 0.f;
  for (int k0 = 0; k0 < HID; k0 += 16){
    int m0 = rb + lr, m1 = rb + lr + 16;
    float v0 = 0.f, v1 = 0.f;
    if (m0 < 336) v0 = Wm[((long)l*336 + m0)*HID + k0 + lk];
    else if (m0 == 336) v0 = bm[l*HID + k0 + lk];
    if (m1 < 336) v1 = Wm[((long)l*336 + m1)*HID + k0 + lk];
    else if (m1 == 336) v1 = bm[l*HID + k0 + lk];
    a_s[lk*36 + lr]      = v0;
    a_s[lk*36 + lr + 16] = v1;
    #pragma unroll
    for (int q = 0; q < 8; ++q)
      w_s[(wk + 2*q)*128 + wcc] = Wxb[(k0 + wk + 2*q)*HD + wcc];
    __syncthreads();
    #pragma unroll
    for (int k = 0; k < 16; ++k){
      float4 av = *(const float4*)&a_s[k*36 + rg*4];
      float4 wv = *(const float4*)&w_s[k*128 + cg*4];
      acc[0][0] += av.x*wv.x; acc[0][1] += av.x*wv.y; acc[0][2] += av.x*wv.z; acc[0][3] += av.x*wv.w;
      acc[1][0] += av.y*wv.x; acc[1][1] += av.y*wv.y; acc[1][2] += av.y*wv.z; acc[1][3] += av.y*wv.w;
      acc[2][0] += av.z*wv.x; acc[2][1] += av.z*wv.y; acc[2][2] += av.z*wv.z; acc[2][3] += av.z*wv.w;
      acc[3][0] += av.w*wv.x; acc[3][1] += av.w*wv.y; acc[3][2] += av.w*wv.z; acc[3][3] += av.w*wv.w;
    }
    __syncthreads();
  }
  #pragma unroll
  for (int i = 0; i < 4; ++i){
    int m = rb + rg*4 + i;
    if (m < 337){
      #pragma unroll
      for (int j = 0; j < 4; ++j)
        WcT[((long)l*HD + cg*4 + j)*KP + 128 + m] = f2bs(acc[i][j]);
    }
  }
}

// ---- fused per-layer kernel: edge aggregation (-> LDS A tile) + MFMA GEMM ----
// 2500 blocks x 256 thr; 4 nodes/block (one wave per node); 4x16-lane quarters per node
template<int FIRST, int FINAL>
__global__ __launch_bounds__(256) void k_layer(const uint4* __restrict__ xb4, const float* __restrict__ posf_cur,
                                               const int* __restrict__ row_ptr, const int* __restrict__ sj,
                                               const int* __restrict__ se, const float* __restrict__ ea,
                                               ushort_t* __restrict__ inv,
                                               const ushort_t* __restrict__ WcT, const float* __restrict__ bx,
                                               ushort_t* __restrict__ xb_next, const float* __restrict__ x_ori,
                                               float* __restrict__ out, float* __restrict__ posf_next){
  __shared__ ushort_t Asm[4*AST];
  int tid = threadIdx.x;
  int nl  = tid >> 6;                       // node-local 0..3 (== wave)
  int n   = blockIdx.x*4 + nl;
  int sub = tid & 63;
  int g   = sub >> 4;                       // quarter of edge list 0..3
  int gl  = sub & 15;                       // lane in group
  int beg = row_ptr[n], end = row_ptr[n+1];
  int len = end - beg;
  int q0 = beg + ((len * g) >> 2);
  int q1 = beg + ((len * (g+1)) >> 2);

  uint4 xi = xb4[(long)n*16 + gl];
  float2 xi0 = cvt2(xi.x), xi1 = cvt2(xi.y), xi2 = cvt2(xi.z), xi3 = cvt2(xi.w);
  float c0 = (10.0f/63.0f)*(float)(4*gl);
  float c1 = (10.0f/63.0f)*(float)(4*gl+1);
  float c2 = (10.0f/63.0f)*(float)(4*gl+2);
  float c3 = (10.0f/63.0f)*(float)(4*gl+3);

  float2 s0 = {0,0}, s1 = {0,0}, s2 = {0,0}, s3 = {0,0};
  float h0 = 0, h1 = 0, h2 = 0, h3 = 0, sp = 0, sea = 0;

#define EPROC(Bv, Jv, Ev) { \
    float2 e0=cvt2(Bv.x), e1=cvt2(Bv.y), e2=cvt2(Bv.z), e3=cvt2(Bv.w); \
    float d, p=0.f; \
    d=xi0.x-e0.x; p+=d*d;  d=xi0.y-e0.y; p+=d*d; \
    d=xi1.x-e1.x; p+=d*d;  d=xi1.y-e1.y; p+=d*d; \
    d=xi2.x-e2.x; p+=d*d;  d=xi2.y-e2.y; p+=d*d; \
    d=xi3.x-e3.x; p+=d*d;  d=xi3.y-e3.y; p+=d*d; \
    p += __shfl_xor(p,1,64); p += __shfl_xor(p,2,64); \
    p += __shfl_xor(p,4,64); p += __shfl_xor(p,8,64); \
    float r = sqrtf(p); \
    float t0=r-c0, t1=r-c1, t2=r-c2, t3=r-c3; \
    h0 += __expf(-10.f*t0*t0); h1 += __expf(-10.f*t1*t1); \
    h2 += __expf(-10.f*t2*t2); h3 += __expf(-10.f*t3*t3); \
    s0.x+=e0.x; s0.y+=e0.y; s1.x+=e1.x; s1.y+=e1.y; \
    s2.x+=e2.x; s2.y+=e2.y; s3.x+=e3.x; s3.y+=e3.y; \
    if (FIRST) sea += ea[(long)(Ev)*ED + gl]; \
    if (gl < 3) sp += posf_cur[(long)Jv*3 + gl]; }

  int idx = q0;
  for (; idx + 3 < q1; idx += 4){
    int j0 = sj[idx], j1 = sj[idx+1], j2 = sj[idx+2], j3 = sj[idx+3];
    int e0i = FIRST ? se[idx]   : 0;
    int e1i = FIRST ? se[idx+1] : 0;
    int e2i = FIRST ? se[idx+2] : 0;
    int e3i = FIRST ? se[idx+3] : 0;
    uint4 B0 = xb4[(long)j0*16 + gl];
    uint4 B1 = xb4[(long)j1*16 + gl];
    uint4 B2 = xb4[(long)j2*16 + gl];
    uint4 B3 = xb4[(long)j3*16 + gl];
    EPROC(B0, j0, e0i); EPROC(B1, j1, e1i); EPROC(B2, j2, e2i); EPROC(B3, j3, e3i);
  }
  for (; idx < q1; ++idx){
    int j0 = sj[idx];
    int e0i = FIRST ? se[idx] : 0;
    uint4 B0 = xb4[(long)j0*16 + gl];
    EPROC(B0, j0, e0i);
  }
#undef EPROC

  // combine quarters (xor 16, then xor 32: sums lanes gl, gl+16, gl+32, gl+48)
  s0.x += __shfl_xor(s0.x,16,64); s0.y += __shfl_xor(s0.y,16,64);
  s1.x += __shfl_xor(s1.x,16,64); s1.y += __shfl_xor(s1.y,16,64);
  s2.x += __shfl_xor(s2.x,16,64); s2.y += __shfl_xor(s2.y,16,64);
  s3.x += __shfl_xor(s3.x,16,64); s3.y += __shfl_xor(s3.y,16,64);
  h0 += __shfl_xor(h0,16,64); h1 += __shfl_xor(h1,16,64);
  h2 += __shfl_xor(h2,16,64); h3 += __shfl_xor(h3,16,64);
  sp += __shfl_xor(sp,16,64);
  if (FIRST) sea += __shfl_xor(sea,16,64);
  s0.x += __shfl_xor(s0.x,32,64); s0.y += __shfl_xor(s0.y,32,64);
  s1.x += __shfl_xor(s1.x,32,64); s1.y += __shfl_xor(s1.y,32,64);
  s2.x += __shfl_xor(s2.x,32,64); s2.y += __shfl_xor(s2.y,32,64);
  s3.x += __shfl_xor(s3.x,32,64); s3.y += __shfl_xor(s3.y,32,64);
  h0 += __shfl_xor(h0,32,64); h1 += __shfl_xor(h1,32,64);
  h2 += __shfl_xor(h2,32,64); h3 += __shfl_xor(h3,32,64);
  sp += __shfl_xor(sp,32,64);
  if (FIRST) sea += __shfl_xor(sea,32,64);

  if (g == 0){
    float cf = (float)len;
    ushort_t* Ar = Asm + nl*AST;
    ((uint4*)Ar)[gl] = xi;
    ((uint4*)(Ar + 128))[gl] = make_uint4(pack2u(cf*xi0.x, cf*xi0.y), pack2u(cf*xi1.x, cf*xi1.y),
                                          pack2u(cf*xi2.x, cf*xi2.y), pack2u(cf*xi3.x, cf*xi3.y));
    ((uint4*)(Ar + 256))[gl] = make_uint4(pack2u(s0.x, s0.y), pack2u(s1.x, s1.y),
                                          pack2u(s2.x, s2.y), pack2u(s3.x, s3.y));
    ((uint2*)(Ar + 384))[gl] = make_uint2(pack2u(h0, h1), pack2u(h2, h3));
    ushort_t sea_us;
    if (FIRST){
      sea_us = f2bs(sea);
      inv[(long)n*16 + gl] = sea_us;
    } else {
      sea_us = inv[(long)n*16 + gl];
    }
    Ar[448 + gl] = sea_us;
    Ar[464 + gl] = (gl == 0) ? f2bs(cf) : (ushort_t)0;
    if (gl < 3){
      float pi = posf_cur[n*3 + gl];
      posf_next[n*3 + gl] = pi + (cf*pi - sp) / fmaxf(cf, 1.f);
    }
  }
  __syncthreads();

  // ---- phase B: MFMA GEMM, M=16 tile (rows repeat the block's 4 nodes), cols = wave*32..+32 ----
  int wave = tid >> 6, lane = tid & 63;
  int quad = lane >> 4, l16 = lane & 15;
  int nb = wave * 32;
  const ushort_t* Arow = Asm + (l16 & 3)*AST + quad*8;
  const ushort_t* W0 = WcT + (long)(nb + l16)*KP + quad*8;
  const ushort_t* W1 = WcT + (long)(nb + 16 + l16)*KP + quad*8;
  f32x4 acc0 = {0,0,0,0}, acc1 = {0,0,0,0};
  for (int k0 = 0; k0 < KP; k0 += 32){
    short8 av = *(const short8*)(Arow + k0);
    short8 b0 = *(const short8*)(W0 + k0);
    short8 b1 = *(const short8*)(W1 + k0);
    acc0 = __builtin_amdgcn_mfma_f32_16x16x32_bf16(av, b0, acc0, 0, 0, 0);
    acc1 = __builtin_amdgcn_mfma_f32_16x16x32_bf16(av, b1, acc1, 0, 0, 0);
  }
  // rows 0..3 of the D tile are nodes 0..3 of this block (rows repeat with period 4)
  if (quad == 0){
    float bx0 = bx[nb + l16], bx1 = bx[nb + 16 + l16];
    #pragma unroll
    for (int r = 0; r < 4; ++r){
      long base = (long)(blockIdx.x*4 + r)*HD;
      float v0 = leaky(acc0[r] + bx0);
      float v1 = leaky(acc1[r] + bx1);
      if (FINAL){
        out[base + nb + l16]      = leaky(x_ori[base + nb + l16] + v0);
        out[base + nb + 16 + l16] = leaky(x_ori[base + nb + 16 + l16] + v1);
      } else {
        xb_next[base + nb + l16]      = f2bs(v0);
        xb_next[base + nb + 16 + l16] = f2bs(v1);
      }
    }
  }
}

extern "C" void kernel_launch(void* const* d_in, const int* in_sizes, int n_in,
                              void* d_out, int out_size, void* d_ws, size_t ws_size,
                              hipStream_t stream){
  const float* x   = (const float*)d_in[0];
  const float* pos = (const float*)d_in[1];
  const int*   ei  = (const int*)d_in[2];
  const float* ea  = (const float*)d_in[3];
  const float* Wm  = (const float*)d_in[4];
  const float* bm  = (const float*)d_in[5];
  const float* Wx  = (const float*)d_in[8];
  const float* bx  = (const float*)d_in[9];
  float* out_x   = (float*)d_out;
  float* out_pos = out_x + NN*HD;

  ushort_t* xbA    = (ushort_t*)d_ws;
  ushort_t* xbB    = xbA + NN*HD;
  ushort_t* WcT    = xbB + NN*HD;
  ushort_t* inv    = WcT + 4*HD*KP;
  float*    pfA    = (float*)(inv + NN*16);
  float*    pfB    = pfA + NN*3;
  int*      cnt    = (int*)(pfB + NN*3);
  int*      c2     = cnt + NN;
  int*      row_ptr= c2 + NN;
  int*      sj     = row_ptr + (NN+1);
  int*      se     = sj + NE;
  const int* ii = ei;
  const int* jj = ei + NE;

  hipMemsetAsync(cnt, 0, 2*NN*sizeof(int), stream);
  int misc_threads = NN*HD + NE + 4*HD*HD + 4*HD*15;
  k_misc  <<<(misc_threads + 255)/256, 256, 0, stream>>>(x, xbA, ii, cnt, Wx, WcT);
  k_scan  <<<1, 256, 0, stream>>>(cnt, row_ptr);
  k_fillwc<<<1250 + 44, 256, 0, stream>>>(ii, jj, row_ptr, c2, sj, se, Wm, bm, Wx, WcT);

  const float* ps[4] = {pos, pfA, pfB, pfA};
  float*       pd[4] = {pfA, pfB, pfA, out_pos};

  k_layer<1,0><<<2500, 256, 0, stream>>>((const uint4*)xbA, ps[0], row_ptr, sj, se, ea, inv,
                                         WcT + 0*HD*KP, bx + 0*HD, xbB, x, out_x, pd[0]);
  k_layer<0,0><<<2500, 256, 0, stream>>>((const uint4*)xbB, ps[1], row_ptr, sj, se, ea, inv,
                                         WcT + 1*(long)HD*KP, bx + 1*HD, xbA, x, out_x, pd[1]);
  k_layer<0,0><<<2500, 256, 0, stream>>>((const uint4*)xbA, ps[2], row_ptr, sj, se, ea, inv,
                                         WcT + 2*(long)HD*KP, bx + 2*HD, xbB, x, out_x, pd[2]);
  k_layer<0,1><<<2500, 256, 0, stream>>>((const uint4*)xbB, ps[3], row_ptr, sj, se, ea, inv,
                                         WcT + 3*(long)HD*KP, bx + 3*HD, xbA, x, out_x, pd[3]);
}

// Round 9
// 343.536 us; speedup vs baseline: 1.0160x; 1.0160x over previous
//
#include <hip/hip_runtime.h>
#include <hip/hip_bf16.h>

#define NN 10000      // nodes
#define NE 320000     // edges
#define HD 128        // h_dim
#define ED 16         // e_dim
#define HID 256       // hid_dim
#define KP 480        // A row: [x 128 | cnt*x 128 | sum_xj 128 | sum_soh 64 | sum_ea 16 | cnt 1 | pad 15]
#define AST 488       // LDS A-row stride (ushorts), 976B = 16B-aligned

typedef unsigned short ushort_t;
typedef __attribute__((ext_vector_type(8))) short short8;
typedef __attribute__((ext_vector_type(4))) float f32x4;

__device__ __forceinline__ float leaky(float v){ return v > 0.f ? v : 0.01f*v; }
__device__ __forceinline__ ushort_t f2bs(float v){
  __hip_bfloat16 b = __float2bfloat16(v);
  return *(ushort_t*)&b;
}
__device__ __forceinline__ unsigned pack2u(float a, float b){
  return (unsigned)f2bs(a) | ((unsigned)f2bs(b) << 16);
}
__device__ __forceinline__ float bl(unsigned u){ return __uint_as_float(u << 16); }
__device__ __forceinline__ float bh(unsigned u){ return __uint_as_float(u & 0xffff0000u); }
__device__ __forceinline__ float2 cvt2(unsigned u){ return make_float2(bl(u), bh(u)); }

// ---- merged setup: seed x->bf16 | edge count | wc_top transpose | WcT K-pad zeros ----
__global__ __launch_bounds__(256) void k_misc(const float* __restrict__ x, ushort_t* __restrict__ xb,
                                              const int* __restrict__ ii, int* __restrict__ cnt,
                                              const float* __restrict__ Wx, ushort_t* __restrict__ WcT){
  int t = blockIdx.x*256 + threadIdx.x;
  if (t < NN*HD){
    xb[t] = f2bs(x[t]);
  } else if (t < NN*HD + NE){
    atomicAdd(&cnt[ii[t - NN*HD]], 1);
  } else if (t < NN*HD + NE + 4*HD*HD){
    int u = t - NN*HD - NE;
    int l = u >> 14, r = (u >> 7) & 127, c = u & 127;
    WcT[((long)l*HD + c)*KP + r] = f2bs(Wx[(long)l*(HD+HID)*HD + r*HD + c]);
  } else {
    int u = t - NN*HD - NE - 4*HD*HD;     // 512 rows x 15 pad cols
    if (u < 4*HD*15){
      int row = u / 15, k = 465 + u % 15;
      WcT[(long)row*KP + k] = 0;
    }
  }
}

__global__ __launch_bounds__(256) void k_scan(const int* __restrict__ cnt, int* __restrict__ row_ptr){
  const int PER = 40;
  __shared__ int sh[256];
  int t = threadIdx.x;
  int base = t*PER;
  int s = 0;
  for (int k = 0; k < PER; ++k){ int idx = base+k; if (idx < NN) s += cnt[idx]; }
  sh[t] = s; __syncthreads();
  for (int off = 1; off < 256; off <<= 1){
    int v = (t >= off) ? sh[t-off] : 0;
    __syncthreads();
    sh[t] += v;
    __syncthreads();
  }
  int pre = sh[t] - s;
  for (int k = 0; k < PER; ++k){
    int idx = base+k;
    if (idx < NN){ row_ptr[idx] = pre; pre += cnt[idx]; }
  }
  if (t == 255) row_ptr[NN] = sh[255];
}

// ---- merged: CSR fill (blocks 0..1249) | wc_bot GEMM (blocks 1250..1293) ----
__global__ __launch_bounds__(256) void k_fillwc(const int* __restrict__ ii, const int* __restrict__ jj,
                                                const int* __restrict__ row_ptr, int* __restrict__ c2,
                                                int* __restrict__ sj, int* __restrict__ se,
                                                const float* __restrict__ Wm, const float* __restrict__ bm,
                                                const float* __restrict__ Wx, ushort_t* __restrict__ WcT){
  if (blockIdx.x < 1250){
    int e = blockIdx.x*256 + threadIdx.x;   // 1250*256 == NE exactly
    int a = ii[e];
    int p = atomicAdd(&c2[a], 1);
    int idx = row_ptr[a] + p;
    sj[idx] = jj[e];
    se[idx] = e;
    return;
  }
  __shared__ float a_s[16*36];
  __shared__ float w_s[16*128];
  int bi = blockIdx.x - 1250;
  int t  = threadIdx.x;
  int rb = (bi % 11) * 32;
  int l  = bi / 11;
  int lr = t >> 4, lk = t & 15;
  int wcc = t & 127, wk = t >> 7;
  int cg = t & 31, rg = t >> 5;
  const float* Wxb = Wx + (long)l*(HD+HID)*HD + HD*HD;
  float acc[4][4];
  #pragma unroll
  for (int i = 0; i < 4; ++i)
    #pragma unroll
    for (int j = 0; j < 4; ++j) acc[i][j] = 0.f;
  for (int k0 = 0; k0 < HID; k0 += 16){
    int m0 = rb + lr, m1 = rb + lr + 16;
    float v0 = 0.f, v1 = 0.f;
    if (m0 < 336) v0 = Wm[((long)l*336 + m0)*HID + k0 + lk];
    else if (m0 == 336) v0 = bm[l*HID + k0 + lk];
    if (m1 < 336) v1 = Wm[((long)l*336 + m1)*HID + k0 + lk];
    else if (m1 == 336) v1 = bm[l*HID + k0 + lk];
    a_s[lk*36 + lr]      = v0;
    a_s[lk*36 + lr + 16] = v1;
    #pragma unroll
    for (int q = 0; q < 8; ++q)
      w_s[(wk + 2*q)*128 + wcc] = Wxb[(k0 + wk + 2*q)*HD + wcc];
    __syncthreads();
    #pragma unroll
    for (int k = 0; k < 16; ++k){
      float4 av = *(const float4*)&a_s[k*36 + rg*4];
      float4 wv = *(const float4*)&w_s[k*128 + cg*4];
      acc[0][0] += av.x*wv.x; acc[0][1] += av.x*wv.y; acc[0][2] += av.x*wv.z; acc[0][3] += av.x*wv.w;
      acc[1][0] += av.y*wv.x; acc[1][1] += av.y*wv.y; acc[1][2] += av.y*wv.z; acc[1][3] += av.y*wv.w;
      acc[2][0] += av.z*wv.x; acc[2][1] += av.z*wv.y; acc[2][2] += av.z*wv.z; acc[2][3] += av.z*wv.w;
      acc[3][0] += av.w*wv.x; acc[3][1] += av.w*wv.y; acc[3][2] += av.w*wv.z; acc[3][3] += av.w*wv.w;
    }
    __syncthreads();
  }
  #pragma unroll
  for (int i = 0; i < 4; ++i){
    int m = rb + rg*4 + i;
    if (m < 337){
      #pragma unroll
      for (int j = 0; j < 4; ++j)
        WcT[((long)l*HD + cg*4 + j)*KP + 128 + m] = f2bs(acc[i][j]);
    }
  }
}

// ---- fused per-layer kernel: L2-warm + edge aggregation (-> LDS A tile) + MFMA GEMM ----
// 1250 blocks x 256 thr; 8 nodes/block; 16 lanes per node-half
template<int FIRST, int FINAL>
__global__ __launch_bounds__(256) void k_layer(const uint4* __restrict__ xb4, const float* __restrict__ posf_cur,
                                               const int* __restrict__ row_ptr, const int* __restrict__ sj,
                                               const int* __restrict__ se, const float* __restrict__ ea,
                                               ushort_t* __restrict__ inv,
                                               const ushort_t* __restrict__ WcT, const float* __restrict__ bx,
                                               ushort_t* __restrict__ xb_next, const float* __restrict__ x_ori,
                                               float* __restrict__ out, float* __restrict__ posf_next){
  __shared__ ushort_t Asm[8*AST];
  int tid = threadIdx.x;

  // ---- L2-warm: the ~156 blocks on each XCD cooperatively stream the whole x-table ----
  // blockIdx round-robins XCDs; slot = blockIdx>>3 covers chunk [slot*1024, slot*1024+1024)
  // of the 160000-uint4 table, so each XCD's L2 receives the full 2.56 MB as a stream.
  float warm = 0.f;
  {
    long wbase = (long)(blockIdx.x >> 3) * 1024 + tid;
    #pragma unroll
    for (int k = 0; k < 4; ++k){
      long off = wbase + k*256;
      if (off < (long)NN*16){
        uint4 v = xb4[off];
        warm += (float)(v.x ^ v.y ^ v.z ^ v.w);
      }
    }
  }

  int nl  = tid >> 5;                       // node-local 0..7
  int n   = blockIdx.x*8 + nl;
  int sub = tid & 31;
  int g   = sub >> 4;                       // half of edge list
  int gl  = sub & 15;                       // lane in group
  int beg = row_ptr[n], end = row_ptr[n+1];
  int len = end - beg;
  int q0 = beg + ((len * g) >> 1);
  int q1 = beg + ((len * (g+1)) >> 1);

  uint4 xi = xb4[(long)n*16 + gl];
  float2 xi0 = cvt2(xi.x), xi1 = cvt2(xi.y), xi2 = cvt2(xi.z), xi3 = cvt2(xi.w);
  float c0 = (10.0f/63.0f)*(float)(4*gl);
  float c1 = (10.0f/63.0f)*(float)(4*gl+1);
  float c2 = (10.0f/63.0f)*(float)(4*gl+2);
  float c3 = (10.0f/63.0f)*(float)(4*gl+3);

  float2 s0 = {0,0}, s1 = {0,0}, s2 = {0,0}, s3 = {0,0};
  float h0 = 0, h1 = 0, h2 = 0, h3 = 0, sp = 0, sea = 0;

#define EPROC(Bv, Jv, Ev) { \
    float2 e0=cvt2(Bv.x), e1=cvt2(Bv.y), e2=cvt2(Bv.z), e3=cvt2(Bv.w); \
    float d, p=0.f; \
    d=xi0.x-e0.x; p+=d*d;  d=xi0.y-e0.y; p+=d*d; \
    d=xi1.x-e1.x; p+=d*d;  d=xi1.y-e1.y; p+=d*d; \
    d=xi2.x-e2.x; p+=d*d;  d=xi2.y-e2.y; p+=d*d; \
    d=xi3.x-e3.x; p+=d*d;  d=xi3.y-e3.y; p+=d*d; \
    p += __shfl_xor(p,1,64); p += __shfl_xor(p,2,64); \
    p += __shfl_xor(p,4,64); p += __shfl_xor(p,8,64); \
    float r = sqrtf(p); \
    float t0=r-c0, t1=r-c1, t2=r-c2, t3=r-c3; \
    h0 += __expf(-10.f*t0*t0); h1 += __expf(-10.f*t1*t1); \
    h2 += __expf(-10.f*t2*t2); h3 += __expf(-10.f*t3*t3); \
    s0.x+=e0.x; s0.y+=e0.y; s1.x+=e1.x; s1.y+=e1.y; \
    s2.x+=e2.x; s2.y+=e2.y; s3.x+=e3.x; s3.y+=e3.y; \
    if (FIRST) sea += ea[(long)(Ev)*ED + gl]; \
    if (gl < 3) sp += posf_cur[(long)Jv*3 + gl]; }

  int idx = q0;
  for (; idx + 3 < q1; idx += 4){
    int j0 = sj[idx], j1 = sj[idx+1], j2 = sj[idx+2], j3 = sj[idx+3];
    int e0i = FIRST ? se[idx]   : 0;
    int e1i = FIRST ? se[idx+1] : 0;
    int e2i = FIRST ? se[idx+2] : 0;
    int e3i = FIRST ? se[idx+3] : 0;
    uint4 B0 = xb4[(long)j0*16 + gl];
    uint4 B1 = xb4[(long)j1*16 + gl];
    uint4 B2 = xb4[(long)j2*16 + gl];
    uint4 B3 = xb4[(long)j3*16 + gl];
    EPROC(B0, j0, e0i); EPROC(B1, j1, e1i); EPROC(B2, j2, e2i); EPROC(B3, j3, e3i);
  }
  for (; idx < q1; ++idx){
    int j0 = sj[idx];
    int e0i = FIRST ? se[idx] : 0;
    uint4 B0 = xb4[(long)j0*16 + gl];
    EPROC(B0, j0, e0i);
  }
#undef EPROC

  // combine halves (xor 16 swaps g0<->g1 within each 32-lane pair)
  s0.x += __shfl_xor(s0.x,16,64); s0.y += __shfl_xor(s0.y,16,64);
  s1.x += __shfl_xor(s1.x,16,64); s1.y += __shfl_xor(s1.y,16,64);
  s2.x += __shfl_xor(s2.x,16,64); s2.y += __shfl_xor(s2.y,16,64);
  s3.x += __shfl_xor(s3.x,16,64); s3.y += __shfl_xor(s3.y,16,64);
  h0 += __shfl_xor(h0,16,64); h1 += __shfl_xor(h1,16,64);
  h2 += __shfl_xor(h2,16,64); h3 += __shfl_xor(h3,16,64);
  sp += __shfl_xor(sp,16,64);
  if (FIRST) sea += __shfl_xor(sea,16,64);

  if (g == 0){
    float cf = (float)len;
    ushort_t* Ar = Asm + nl*AST;
    ((uint4*)Ar)[gl] = xi;
    ((uint4*)(Ar + 128))[gl] = make_uint4(pack2u(cf*xi0.x, cf*xi0.y), pack2u(cf*xi1.x, cf*xi1.y),
                                          pack2u(cf*xi2.x, cf*xi2.y), pack2u(cf*xi3.x, cf*xi3.y));
    ((uint4*)(Ar + 256))[gl] = make_uint4(pack2u(s0.x, s0.y), pack2u(s1.x, s1.y),
                                          pack2u(s2.x, s2.y), pack2u(s3.x, s3.y));
    ((uint2*)(Ar + 384))[gl] = make_uint2(pack2u(h0, h1), pack2u(h2, h3));
    ushort_t sea_us;
    if (FIRST){
      sea_us = f2bs(sea);
      inv[(long)n*16 + gl] = sea_us;
    } else {
      sea_us = inv[(long)n*16 + gl];
    }
    Ar[448 + gl] = sea_us;
    Ar[464 + gl] = (gl == 0) ? f2bs(cf) : (ushort_t)0;
    if (gl < 3){
      float pi = posf_cur[n*3 + gl];
      posf_next[n*3 + gl] = pi + (cf*pi - sp) / fmaxf(cf, 1.f);
    }
  }
  __syncthreads();

  // ---- phase B: MFMA GEMM, M=16 tile (top 8 rows real), cols = wave*32..+32 ----
  int wave = tid >> 6, lane = tid & 63;
  int quad = lane >> 4, l16 = lane & 15;
  int nb = wave * 32;
  const ushort_t* Arow = Asm + (l16 & 7)*AST + quad*8;
  const ushort_t* W0 = WcT + (long)(nb + l16)*KP + quad*8;
  const ushort_t* W1 = WcT + (long)(nb + 16 + l16)*KP + quad*8;
  f32x4 acc0 = {0,0,0,0}, acc1 = {0,0,0,0};
  for (int k0 = 0; k0 < KP; k0 += 32){
    short8 av = *(const short8*)(Arow + k0);
    short8 b0 = *(const short8*)(W0 + k0);
    short8 b1 = *(const short8*)(W1 + k0);
    acc0 = __builtin_amdgcn_mfma_f32_16x16x32_bf16(av, b0, acc0, 0, 0, 0);
    acc1 = __builtin_amdgcn_mfma_f32_16x16x32_bf16(av, b1, acc1, 0, 0, 0);
  }
  float bx0 = bx[nb + l16], bx1 = bx[nb + 16 + l16];
  #pragma unroll
  for (int r = 0; r < 4; ++r){
    int row = quad*4 + r;
    if (row < 8){
      long base = (long)(blockIdx.x*8 + row)*HD;
      float v0 = leaky(acc0[r] + bx0);
      float v1 = leaky(acc1[r] + bx1);
      if (FINAL){
        out[base + nb + l16]      = leaky(x_ori[base + nb + l16] + v0);
        out[base + nb + 16 + l16] = leaky(x_ori[base + nb + 16 + l16] + v1);
      } else {
        xb_next[base + nb + l16]      = f2bs(v0);
        xb_next[base + nb + 16 + l16] = f2bs(v1);
      }
    }
  }

  // DCE guard for the warm loads (condition can never be true)
  if (warm > 1e30f) Asm[8*AST - 1] = 1;
}

extern "C" void kernel_launch(void* const* d_in, const int* in_sizes, int n_in,
                              void* d_out, int out_size, void* d_ws, size_t ws_size,
                              hipStream_t stream){
  const float* x   = (const float*)d_in[0];
  const float* pos = (const float*)d_in[1];
  const int*   ei  = (const int*)d_in[2];
  const float* ea  = (const float*)d_in[3];
  const float* Wm  = (const float*)d_in[4];
  const float* bm  = (const float*)d_in[5];
  const float* Wx  = (const float*)d_in[8];
  const float* bx  = (const float*)d_in[9];
  float* out_x   = (float*)d_out;
  float* out_pos = out_x + NN*HD;

  ushort_t* xbA    = (ushort_t*)d_ws;
  ushort_t* xbB    = xbA + NN*HD;
  ushort_t* WcT    = xbB + NN*HD;
  ushort_t* inv    = WcT + 4*HD*KP;
  float*    pfA    = (float*)(inv + NN*16);
  float*    pfB    = pfA + NN*3;
  int*      cnt    = (int*)(pfB + NN*3);
  int*      c2     = cnt + NN;
  int*      row_ptr= c2 + NN;
  int*      sj     = row_ptr + (NN+1);
  int*      se     = sj + NE;
  const int* ii = ei;
  const int* jj = ei + NE;

  hipMemsetAsync(cnt, 0, 2*NN*sizeof(int), stream);
  int misc_threads = NN*HD + NE + 4*HD*HD + 4*HD*15;
  k_misc  <<<(misc_threads + 255)/256, 256, 0, stream>>>(x, xbA, ii, cnt, Wx, WcT);
  k_scan  <<<1, 256, 0, stream>>>(cnt, row_ptr);
  k_fillwc<<<1250 + 44, 256, 0, stream>>>(ii, jj, row_ptr, c2, sj, se, Wm, bm, Wx, WcT);

  const float* ps[4] = {pos, pfA, pfB, pfA};
  float*       pd[4] = {pfA, pfB, pfA, out_pos};

  k_layer<1,0><<<1250, 256, 0, stream>>>((const uint4*)xbA, ps[0], row_ptr, sj, se, ea, inv,
                                         WcT + 0*HD*KP, bx + 0*HD, xbB, x, out_x, pd[0]);
  k_layer<0,0><<<1250, 256, 0, stream>>>((const uint4*)xbB, ps[1], row_ptr, sj, se, ea, inv,
                                         WcT + 1*(long)HD*KP, bx + 1*HD, xbA, x, out_x, pd[1]);
  k_layer<0,0><<<1250, 256, 0, stream>>>((const uint4*)xbA, ps[2], row_ptr, sj, se, ea, inv,
                                         WcT + 2*(long)HD*KP, bx + 2*HD, xbB, x, out_x, pd[2]);
  k_layer<0,1><<<1250, 256, 0, stream>>>((const uint4*)xbB, ps[3], row_ptr, sj, se, ea, inv,
                                         WcT + 3*(long)HD*KP, bx + 3*HD, xbA, x, out_x, pd[3]);
}